// Round 1
// baseline (303.632 us; speedup 1.0000x reference)
//
#include <hip/hip_runtime.h>

// SoftmaxCascade: B=8192 rows, E=4681 nodes, 8-ary implicit heap
// (children of p are 8p+1..8p+8; levels at offsets 0,1,9,73,585,4681).
// Per row: per-parent log_softmax over 8 children, accumulate along
// root->node path, exp. Memory-bound: 307 MB total traffic -> ~49us floor.

constexpr int E      = 4681;
constexpr int NGROUP = 585;            // #parents == #sibling-groups of 8
constexpr int LDSN   = 1 + NGROUP * 9; // group g stored at [1+9g, 1+9g+8) (stride-9 pad)

// node index -> padded LDS slot.  i>=1: group g=(i-1)>>3, child k=(i-1)&7,
// slot = 1 + 9g + k = i + g.  Root: slot 0.
__device__ __forceinline__ int lds_idx(int i) {
    return (i == 0) ? 0 : i + ((i - 1) >> 3);
}

__global__ __launch_bounds__(256) void cascade_kernel(const float* __restrict__ in,
                                                      float* __restrict__ out) {
    __shared__ float a[LDSN];
    const int tid = threadIdx.x;
    const long long rowbase = (long long)blockIdx.x * (long long)E;
    const float* __restrict__ rin  = in  + rowbase;
    float* __restrict__       rout = out + rowbase;

    // ---- global -> LDS, float4 with alignment peel ----
    // rowbase mod 4 == blockIdx.x mod 4 (E == 1 mod 4); peel s elems so the
    // vector body starts 16B-aligned.
    const int s = (4 - ((int)(rowbase & 3))) & 3;
    if (tid < s) a[lds_idx(tid)] = rin[tid];
    const int nv4 = (E - s) >> 2;
    const float4* __restrict__ rin4 = (const float4*)(rin + s);
    for (int j = tid; j < nv4; j += 256) {
        float4 v = rin4[j];
        int i = s + 4 * j;
        // consecutive lanes -> lds stride alternating 4/5 -> 2-way max (free)
        a[lds_idx(i)]     = v.x;
        a[lds_idx(i + 1)] = v.y;
        a[lds_idx(i + 2)] = v.z;
        a[lds_idx(i + 3)] = v.w;
    }
    for (int i = s + 4 * nv4 + tid; i < E; i += 256) a[lds_idx(i)] = rin[i];

    // log p(root) = 0 (root's softmax group has one element).
    // Element 0 was written by tid 0 above in every case, so no race.
    if (tid == 0) a[0] = 0.0f;
    __syncthreads();

    // ---- level-by-level: logp[child] = x - m - log(sum) + logp[parent] ----
    // parents of level-l children occupy [OFF[l], OFF[l+1])
    constexpr int OFF[5] = {0, 1, 9, 73, 585};
    #pragma unroll
    for (int l = 0; l < 4; ++l) {
        for (int p = OFF[l] + tid; p < OFF[l + 1]; p += 256) {
            const int cb = 1 + 9 * p;   // children slots, lane-stride 9 -> conflict-free
            float c[8];
            #pragma unroll
            for (int k = 0; k < 8; ++k) c[k] = a[cb + k];
            float m = c[0];
            #pragma unroll
            for (int k = 1; k < 8; ++k) m = fmaxf(m, c[k]);
            float ssum = 0.0f;
            #pragma unroll
            for (int k = 0; k < 8; ++k) ssum += __expf(c[k] - m);
            const float adj = a[lds_idx(p)] - m - __logf(ssum);
            #pragma unroll
            for (int k = 0; k < 8; ++k) a[cb + k] = c[k] + adj;
        }
        __syncthreads();
    }

    // ---- exp + LDS -> global, float4 with same peel ----
    if (tid < s) rout[tid] = __expf(a[lds_idx(tid)]);
    float4* __restrict__ rout4 = (float4*)(rout + s);
    for (int j = tid; j < nv4; j += 256) {
        int i = s + 4 * j;
        float4 v;
        v.x = __expf(a[lds_idx(i)]);
        v.y = __expf(a[lds_idx(i + 1)]);
        v.z = __expf(a[lds_idx(i + 2)]);
        v.w = __expf(a[lds_idx(i + 3)]);
        rout4[j] = v;
    }
    for (int i = s + 4 * nv4 + tid; i < E; i += 256) rout[i] = __expf(a[lds_idx(i)]);
}

extern "C" void kernel_launch(void* const* d_in, const int* in_sizes, int n_in,
                              void* d_out, int out_size, void* d_ws, size_t ws_size,
                              hipStream_t stream) {
    const float* in = (const float*)d_in[0];   // [B, E] float32
    float* out = (float*)d_out;                // [B, E] float32
    const int B = in_sizes[0] / E;             // 8192
    cascade_kernel<<<B, 256, 0, stream>>>(in, out);
}